// Round 3
// baseline (538.744 us; speedup 1.0000x reference)
//
#include <hip/hip_runtime.h>
#include <hip/hip_cooperative_groups.h>

namespace cg = cooperative_groups;

#define H 1024
#define L 512
#define V 50257
#define NB 1024            // cooperative grid: 4 blocks/CU on 256 CUs
#define LOGIT_BLOCKS 2048  // fallback path only

__device__ __forceinline__ float dot4(float4 a, float4 b) {
    return a.x*b.x + a.y*b.y + a.z*b.z + a.w*b.w;
}

__device__ __forceinline__ float wave_reduce_sum(float v) {
    #pragma unroll
    for (int o = 32; o > 0; o >>= 1) v += __shfl_xor(v, o, 64);
    return v;
}

// ---------------- cooperative mega-kernel ----------------
__global__ __launch_bounds__(256, 4)
void k_mega(const int* __restrict__ input, const float* __restrict__ hidden,
            const float* __restrict__ enc, const float* __restrict__ emb,
            const float* __restrict__ attn_w, const float* __restrict__ attn_b,
            const float* __restrict__ comb_w, const float* __restrict__ comb_b,
            const float* __restrict__ w_ih, const float* __restrict__ w_hh,
            const float* __restrict__ b_ih, const float* __restrict__ b_hh,
            const float* __restrict__ out_w, const float* __restrict__ out_b,
            float* __restrict__ out, float* __restrict__ hnew, float* __restrict__ attnw,
            float* __restrict__ scores, float* __restrict__ gh, float* __restrict__ ce,
            float* __restrict__ attn_applied, float* __restrict__ xbuf,
            float* __restrict__ mpart, float* __restrict__ spart) {
    cg::grid_group grid = cg::this_grid();
    __shared__ float s_w[512];
    __shared__ float s_acc[256];
    __shared__ float s_red[16];
    __shared__ float s_scalar;

    int t = threadIdx.x, lane = t & 63, wid = t >> 6, bid = blockIdx.x;
    size_t erow = (size_t)input[0] * H;
    float4 ev = ((const float4*)(emb + erow))[t];
    float4 hv = ((const float4*)hidden)[t];

    // ---- stage 1: scores (512) | gh = w_hh.h0+b_hh (3072) | ce = comb_w[:, :H].e (1024)
    for (int task = bid; task < 4608; task += NB) {
        float acc;
        if (task < 512) {
            const float4* w = (const float4*)(attn_w + (size_t)task * (2 * H));
            acc = dot4(w[t], ev) + dot4(w[256 + t], hv);
        } else if (task < 3584) {
            int j = task - 512;
            acc = dot4(((const float4*)(w_hh + (size_t)j * H))[t], hv);
        } else {
            int hh = task - 3584;
            acc = dot4(((const float4*)(comb_w + (size_t)hh * (2 * H)))[t], ev);
        }
        acc = wave_reduce_sum(acc);
        if (lane == 0) s_red[wid] = acc;
        __syncthreads();
        if (t == 0) {
            float s = s_red[0] + s_red[1] + s_red[2] + s_red[3];
            if (task < 512)       scores[task] = s + attn_b[task];
            else if (task < 3584) { int j = task - 512; gh[j] = s + b_hh[j]; }
            else                  ce[task - 3584] = s;
        }
        __syncthreads();
    }
    grid.sync();

    // ---- stage 2: softmax(scores) -> attnw; attn_applied (64 tasks x 16 cols)
    for (int task = bid; task < 64; task += NB) {
        float s0 = scores[t], s1 = scores[t + 256];
        float m = fmaxf(s0, s1);
        #pragma unroll
        for (int o = 32; o > 0; o >>= 1) m = fmaxf(m, __shfl_xor(m, o, 64));
        if (lane == 0) s_red[wid] = m;
        __syncthreads();
        m = fmaxf(fmaxf(s_red[0], s_red[1]), fmaxf(s_red[2], s_red[3]));
        __syncthreads();
        float e0 = expf(s0 - m), e1 = expf(s1 - m);
        float ss = wave_reduce_sum(e0 + e1);
        if (lane == 0) s_red[wid] = ss;
        __syncthreads();
        ss = s_red[0] + s_red[1] + s_red[2] + s_red[3];
        float inv = 1.f / ss;
        s_w[t] = e0 * inv; s_w[t + 256] = e1 * inv;
        __syncthreads();
        if (task == 0) { attnw[t] = s_w[t]; attnw[t + 256] = s_w[t + 256]; }
        int col = task * 16 + (t & 15);
        int rc  = t >> 4;
        float a = 0.f;
        #pragma unroll 8
        for (int l = rc; l < 512; l += 16) a += s_w[l] * enc[(size_t)l * H + col];
        s_acc[t] = a;
        __syncthreads();
        #pragma unroll
        for (int st = 128; st >= 16; st >>= 1) {
            if (t < st) s_acc[t] += s_acc[t + st];
            __syncthreads();
        }
        if (t < 16) attn_applied[task * 16 + t] = s_acc[t];
        __syncthreads();
    }
    grid.sync();

    // ---- stage 3: x[h] = relu(ce[h] + comb_w[h, H:2H].attn_applied + comb_b[h])
    {
        float4 av = ((const float4*)attn_applied)[t];
        for (int task = bid; task < 1024; task += NB) {
            float acc = dot4(((const float4*)(comb_w + (size_t)task * (2 * H) + H))[t], av);
            acc = wave_reduce_sum(acc);
            if (lane == 0) s_red[wid] = acc;
            __syncthreads();
            if (t == 0)
                xbuf[task] = fmaxf(ce[task] + s_red[0] + s_red[1] + s_red[2] + s_red[3]
                                   + comb_b[task], 0.f);
            __syncthreads();
        }
    }
    grid.sync();

    // ---- stage 4: gi triple + GRU gating -> hnew
    {
        float4 xv = ((const float4*)xbuf)[t];
        for (int task = bid; task < 1024; task += NB) {
            float a0 = dot4(((const float4*)(w_ih + (size_t)task * H))[t], xv);
            float a1 = dot4(((const float4*)(w_ih + (size_t)(H + task) * H))[t], xv);
            float a2 = dot4(((const float4*)(w_ih + (size_t)(2 * H + task) * H))[t], xv);
            a0 = wave_reduce_sum(a0);
            a1 = wave_reduce_sum(a1);
            a2 = wave_reduce_sum(a2);
            if (lane == 0) { s_red[wid*3] = a0; s_red[wid*3+1] = a1; s_red[wid*3+2] = a2; }
            __syncthreads();
            if (t == 0) {
                float g0 = 0.f, g1 = 0.f, g2 = 0.f;
                #pragma unroll
                for (int w2 = 0; w2 < 4; ++w2) {
                    g0 += s_red[w2*3]; g1 += s_red[w2*3+1]; g2 += s_red[w2*3+2];
                }
                float ir = g0 + b_ih[task];
                float iz = g1 + b_ih[H + task];
                float in_ = g2 + b_ih[2 * H + task];
                float r = 1.f / (1.f + expf(-(ir + gh[task])));
                float z = 1.f / (1.f + expf(-(iz + gh[H + task])));
                float n = tanhf(in_ + r * gh[2 * H + task]);
                hnew[task] = (1.f - z) * n + z * hidden[task];
            }
            __syncthreads();
        }
    }
    grid.sync();

    // ---- stage 5: logits + per-block online (m, sumexp)
    {
        float4 h4[4];
        #pragma unroll
        for (int j = 0; j < 4; ++j) h4[j] = ((const float4*)hnew)[j * 64 + lane];
        float m = -INFINITY, s = 0.f;
        int gwave = bid * 4 + wid;
        for (int r = gwave; r < V; r += NB * 4) {
            const float4* row = (const float4*)(out_w + (size_t)r * H);
            float acc = 0.f;
            #pragma unroll
            for (int j = 0; j < 4; ++j) acc += dot4(row[j * 64 + lane], h4[j]);
            acc = wave_reduce_sum(acc);
            float logit = acc + out_b[r];
            if (lane == 0) out[r] = logit;
            if (logit > m) { s = s * expf(m - logit) + 1.f; m = logit; }
            else           { s += expf(logit - m); }
        }
        if (lane == 0) { s_red[wid] = m; s_red[4 + wid] = s; }
        __syncthreads();
        if (t == 0) {
            float M = fmaxf(fmaxf(s_red[0], s_red[1]), fmaxf(s_red[2], s_red[3]));
            float S = 0.f;
            #pragma unroll
            for (int i = 0; i < 4; ++i) S += s_red[4 + i] * expf(s_red[i] - M);
            mpart[bid] = M; spart[bid] = S;
        }
    }
    grid.sync();

    // ---- stage 6: every block merges partials; subtract logZ in place
    {
        float m = -INFINITY, s = 0.f;
        for (int i = t; i < NB; i += 256) {
            float m2 = mpart[i], s2 = spart[i];
            float mm = fmaxf(m, m2);
            if (mm > -INFINITY) s = s * expf(m - mm) + s2 * expf(m2 - mm);
            m = mm;
        }
        #pragma unroll
        for (int o = 32; o > 0; o >>= 1) {
            float m2 = __shfl_xor(m, o, 64), s2 = __shfl_xor(s, o, 64);
            float mm = fmaxf(m, m2);
            if (mm > -INFINITY) s = s * expf(m - mm) + s2 * expf(m2 - mm);
            m = mm;
        }
        if (lane == 0) { s_red[wid] = m; s_red[4 + wid] = s; }
        __syncthreads();
        if (t == 0) {
            float M = fmaxf(fmaxf(s_red[0], s_red[1]), fmaxf(s_red[2], s_red[3]));
            float S = 0.f;
            #pragma unroll
            for (int i = 0; i < 4; ++i) S += s_red[4 + i] * expf(s_red[i] - M);
            s_scalar = M + logf(S);
        }
        __syncthreads();
        float logZ = s_scalar;
        for (int v = bid * 256 + t; v < V; v += NB * 256) out[v] -= logZ;
    }
}

// ---------------- fallback path (proven 6-kernel pipeline) ----------------
__global__ void k_scores(const float* __restrict__ emb, const int* __restrict__ input,
                         const float* __restrict__ hidden, const float* __restrict__ attn_w,
                         const float* __restrict__ attn_b, float* __restrict__ scores) {
    __shared__ float lds[4];
    int l = blockIdx.x, t = threadIdx.x;
    size_t erow = (size_t)input[0] * H;
    const float4* w = (const float4*)(attn_w + (size_t)l * 2 * H);
    float acc = dot4(w[t], ((const float4*)(emb + erow))[t])
              + dot4(w[256 + t], ((const float4*)hidden)[t]);
    acc = wave_reduce_sum(acc);
    if ((t & 63) == 0) lds[t >> 6] = acc;
    __syncthreads();
    if (t == 0) scores[l] = lds[0] + lds[1] + lds[2] + lds[3] + attn_b[l];
}

__global__ void k_attn(const float* __restrict__ scores, const float* __restrict__ enc,
                       float* __restrict__ attn_out, float* __restrict__ attn_applied) {
    __shared__ float w[512];
    __shared__ float red[4];
    __shared__ float acc_lds[256];
    __shared__ float sM, sS;
    int t = threadIdx.x, lane = t & 63, wid = t >> 6;
    float s0 = scores[t], s1 = scores[t + 256];
    float m = fmaxf(s0, s1);
    #pragma unroll
    for (int o = 32; o > 0; o >>= 1) m = fmaxf(m, __shfl_xor(m, o, 64));
    if (lane == 0) red[wid] = m;
    __syncthreads();
    if (t == 0) sM = fmaxf(fmaxf(red[0], red[1]), fmaxf(red[2], red[3]));
    __syncthreads();
    float M = sM;
    float e0 = expf(s0 - M), e1 = expf(s1 - M);
    float s = wave_reduce_sum(e0 + e1);
    if (lane == 0) red[wid] = s;
    __syncthreads();
    if (t == 0) sS = red[0] + red[1] + red[2] + red[3];
    __syncthreads();
    float inv = 1.f / sS;
    w[t] = e0 * inv; w[t + 256] = e1 * inv;
    __syncthreads();
    if (blockIdx.x == 0) { attn_out[t] = w[t]; attn_out[t + 256] = w[t + 256]; }
    int col = blockIdx.x * 16 + (t & 15);
    int rc  = t >> 4;
    float acc = 0.f;
    #pragma unroll 8
    for (int l = rc; l < 512; l += 16) acc += w[l] * enc[(size_t)l * H + col];
    acc_lds[t] = acc;
    __syncthreads();
    #pragma unroll
    for (int st = 128; st >= 16; st >>= 1) {
        if (t < st) acc_lds[t] += acc_lds[t + st];
        __syncthreads();
    }
    if (t < 16) attn_applied[blockIdx.x * 16 + t] = acc_lds[t];
}

__global__ void k_combine(const float* __restrict__ emb, const int* __restrict__ input,
                          const float* __restrict__ attn_applied, const float* __restrict__ comb_w,
                          const float* __restrict__ comb_b, float* __restrict__ x) {
    __shared__ float lds[4];
    int h = blockIdx.x, t = threadIdx.x;
    size_t erow = (size_t)input[0] * H;
    const float4* w = (const float4*)(comb_w + (size_t)h * 2 * H);
    float acc = dot4(w[t], ((const float4*)(emb + erow))[t])
              + dot4(w[256 + t], ((const float4*)attn_applied)[t]);
    acc = wave_reduce_sum(acc);
    if ((t & 63) == 0) lds[t >> 6] = acc;
    __syncthreads();
    if (t == 0) x[h] = fmaxf(lds[0] + lds[1] + lds[2] + lds[3] + comb_b[h], 0.f);
}

__global__ void k_gru_fused(const float* __restrict__ w_ih, const float* __restrict__ w_hh,
                            const float* __restrict__ b_ih, const float* __restrict__ b_hh,
                            const float* __restrict__ x, const float* __restrict__ hidden,
                            float* __restrict__ hnew) {
    __shared__ float lds[4][6];
    int h = blockIdx.x, t = threadIdx.x, lane = t & 63, wid = t >> 6;
    float4 xv = ((const float4*)x)[t];
    float4 hv = ((const float4*)hidden)[t];
    const float* rows[6] = {
        w_ih + (size_t)h * H, w_ih + (size_t)(H + h) * H, w_ih + (size_t)(2 * H + h) * H,
        w_hh + (size_t)h * H, w_hh + (size_t)(H + h) * H, w_hh + (size_t)(2 * H + h) * H };
    float acc[6];
    #pragma unroll
    for (int k = 0; k < 6; ++k) {
        float4 wv = ((const float4*)rows[k])[t];
        acc[k] = dot4(wv, (k < 3) ? xv : hv);
        acc[k] = wave_reduce_sum(acc[k]);
    }
    if (lane == 0) {
        #pragma unroll
        for (int k = 0; k < 6; ++k) lds[wid][k] = acc[k];
    }
    __syncthreads();
    if (t == 0) {
        float g[6];
        #pragma unroll
        for (int k = 0; k < 6; ++k) g[k] = lds[0][k] + lds[1][k] + lds[2][k] + lds[3][k];
        float r = 1.f / (1.f + expf(-(g[0] + b_ih[h] + g[3] + b_hh[h])));
        float z = 1.f / (1.f + expf(-(g[1] + b_ih[H + h] + g[4] + b_hh[H + h])));
        float n = tanhf(g[2] + b_ih[2 * H + h] + r * (g[5] + b_hh[2 * H + h]));
        hnew[h] = (1.f - z) * n + z * hidden[h];
    }
}

__global__ void k_logits_lse(const float* __restrict__ out_w, const float* __restrict__ out_b,
                             const float* __restrict__ hvec, float* __restrict__ logits,
                             float* __restrict__ mpart, float* __restrict__ spart) {
    __shared__ float lm[4], ls[4];
    int lane = threadIdx.x & 63, wid = threadIdx.x >> 6;
    int gwave = blockIdx.x * 4 + wid;
    const int nwaves = LOGIT_BLOCKS * 4;
    float4 h4[4];
    #pragma unroll
    for (int j = 0; j < 4; ++j) h4[j] = ((const float4*)hvec)[j * 64 + lane];
    float m = -INFINITY, s = 0.f;
    for (int r = gwave; r < V; r += nwaves) {
        const float4* row = (const float4*)(out_w + (size_t)r * H);
        float acc = 0.f;
        #pragma unroll
        for (int j = 0; j < 4; ++j) acc += dot4(row[j * 64 + lane], h4[j]);
        acc = wave_reduce_sum(acc);
        float logit = acc + out_b[r];
        if (lane == 0) logits[r] = logit;
        if (logit > m) { s = s * expf(m - logit) + 1.f; m = logit; }
        else           { s += expf(logit - m); }
    }
    if (lane == 0) { lm[wid] = m; ls[wid] = s; }
    __syncthreads();
    if (threadIdx.x == 0) {
        float M = fmaxf(fmaxf(lm[0], lm[1]), fmaxf(lm[2], lm[3]));
        float S = 0.f;
        if (M > -INFINITY) {
            #pragma unroll
            for (int i = 0; i < 4; ++i) S += ls[i] * expf(lm[i] - M);
        }
        mpart[blockIdx.x] = M; spart[blockIdx.x] = S;
    }
}

__global__ void k_finalize(const float* __restrict__ mpart, const float* __restrict__ spart,
                           float* __restrict__ out) {
    __shared__ float lm[4], ls[4];
    __shared__ float sLogZ;
    int t = threadIdx.x, lane = t & 63, wid = t >> 6;
    float m = -INFINITY, s = 0.f;
    for (int i = t; i < LOGIT_BLOCKS; i += 256) {
        float m2 = mpart[i], s2 = spart[i];
        float mm = fmaxf(m, m2);
        if (mm > -INFINITY) s = s * expf(m - mm) + s2 * expf(m2 - mm);
        m = mm;
    }
    #pragma unroll
    for (int o = 32; o > 0; o >>= 1) {
        float m2 = __shfl_xor(m, o, 64), s2 = __shfl_xor(s, o, 64);
        float mm = fmaxf(m, m2);
        if (mm > -INFINITY) s = s * expf(m - mm) + s2 * expf(m2 - mm);
        m = mm;
    }
    if (lane == 0) { lm[wid] = m; ls[wid] = s; }
    __syncthreads();
    if (t == 0) {
        float M = fmaxf(fmaxf(lm[0], lm[1]), fmaxf(lm[2], lm[3]));
        float S = 0.f;
        #pragma unroll
        for (int i = 0; i < 4; ++i) S += ls[i] * expf(lm[i] - M);
        sLogZ = M + logf(S);
    }
    __syncthreads();
    int v = blockIdx.x * 256 + t;
    if (v < V) out[v] -= sLogZ;
}

extern "C" void kernel_launch(void* const* d_in, const int* in_sizes, int n_in,
                              void* d_out, int out_size, void* d_ws, size_t ws_size,
                              hipStream_t stream) {
    const int*   input  = (const int*)  d_in[0];
    const float* hidden = (const float*)d_in[1];
    const float* enc    = (const float*)d_in[2];
    const float* emb    = (const float*)d_in[3];
    const float* attn_w = (const float*)d_in[4];
    const float* attn_b = (const float*)d_in[5];
    const float* comb_w = (const float*)d_in[6];
    const float* comb_b = (const float*)d_in[7];
    const float* w_ih   = (const float*)d_in[8];
    const float* w_hh   = (const float*)d_in[9];
    const float* b_ih   = (const float*)d_in[10];
    const float* b_hh   = (const float*)d_in[11];
    const float* out_w  = (const float*)d_in[12];
    const float* out_b  = (const float*)d_in[13];

    float* out   = (float*)d_out;            // [0, V)      log_softmax
    float* hnew  = out + V;                  // [V, V+H)    h_new
    float* attnw = out + V + H;              // [V+H, +L)   attn_weights

    float* ws           = (float*)d_ws;
    float* scores       = ws;                // 512
    float* gh           = ws + 512;          // 3072
    float* ce           = ws + 3584;         // 1024
    float* attn_applied = ws + 4608;         // 1024
    float* xbuf         = ws + 5632;         // 1024
    float* mpart        = ws + 6656;         // 1024 (mega)
    float* spart        = ws + 7680;         // 1024 (mega)
    float* mpart2       = ws + 8704;         // 2048 (fallback)
    float* spart2       = ws + 10752;        // 2048 (fallback)

    void* args[] = {
        (void*)&input, (void*)&hidden, (void*)&enc, (void*)&emb,
        (void*)&attn_w, (void*)&attn_b, (void*)&comb_w, (void*)&comb_b,
        (void*)&w_ih, (void*)&w_hh, (void*)&b_ih, (void*)&b_hh,
        (void*)&out_w, (void*)&out_b,
        (void*)&out, (void*)&hnew, (void*)&attnw,
        (void*)&scores, (void*)&gh, (void*)&ce, (void*)&attn_applied,
        (void*)&xbuf, (void*)&mpart, (void*)&spart };

    hipError_t err = hipLaunchCooperativeKernel((const void*)k_mega, dim3(NB), dim3(256),
                                                args, 0, stream);
    if (err != hipSuccess) {
        // fallback: proven 6-dispatch pipeline
        k_scores     <<<512, 256, 0, stream>>>(emb, input, hidden, attn_w, attn_b, scores);
        k_attn       <<<64, 256, 0, stream>>>(scores, enc, attnw, attn_applied);
        k_combine    <<<1024, 256, 0, stream>>>(emb, input, attn_applied, comb_w, comb_b, xbuf);
        k_gru_fused  <<<1024, 256, 0, stream>>>(w_ih, w_hh, b_ih, b_hh, xbuf, hidden, hnew);
        k_logits_lse <<<LOGIT_BLOCKS, 256, 0, stream>>>(out_w, out_b, hnew, out, mpart2, spart2);
        k_finalize   <<<(V + 255) / 256, 256, 0, stream>>>(mpart2, spart2, out);
    }
}

// Round 4
// 59.826 us; speedup vs baseline: 9.0052x; 9.0052x over previous
//
#include <hip/hip_runtime.h>

#define H 1024
#define L 512
#define V 50257
#define LOGIT_BLOCKS 2048   // 4 waves each -> 8192 waves = 32/CU

__device__ __forceinline__ float dot4(float4 a, float4 b) {
    return a.x*b.x + a.y*b.y + a.z*b.z + a.w*b.w;
}

__device__ __forceinline__ float wave_reduce_sum(float v) {
    #pragma unroll
    for (int o = 32; o > 0; o >>= 1) v += __shfl_xor(v, o, 64);
    return v;
}

// D1: all input-only GEMVs in one wide dispatch.
//   task <  512          : scores[task] = attn_w[task,:H].e + attn_w[task,H:].h0 + attn_b
//   512 <= task < 3584   : gh[j] = w_hh[j].h0 + b_hh[j]           (j = task-512)
//   3584 <= task < 4608  : ce[h] = comb_w[h,:H].e                 (h = task-3584)
__global__ void k_pre(const float* __restrict__ emb, const int* __restrict__ input,
                      const float* __restrict__ hidden, const float* __restrict__ attn_w,
                      const float* __restrict__ attn_b, const float* __restrict__ w_hh,
                      const float* __restrict__ b_hh, const float* __restrict__ comb_w,
                      float* __restrict__ scores, float* __restrict__ gh, float* __restrict__ ce) {
    __shared__ float red[4];
    int task = blockIdx.x, t = threadIdx.x, lane = t & 63, wid = t >> 6;
    size_t erow = (size_t)input[0] * H;
    float acc;
    if (task < 512) {
        const float4* w = (const float4*)(attn_w + (size_t)task * (2 * H));
        acc = dot4(w[t], ((const float4*)(emb + erow))[t])
            + dot4(w[256 + t], ((const float4*)hidden)[t]);
    } else if (task < 3584) {
        int j = task - 512;
        acc = dot4(((const float4*)(w_hh + (size_t)j * H))[t], ((const float4*)hidden)[t]);
    } else {
        int h = task - 3584;
        acc = dot4(((const float4*)(comb_w + (size_t)h * (2 * H)))[t], ((const float4*)(emb + erow))[t]);
    }
    acc = wave_reduce_sum(acc);
    if (lane == 0) red[wid] = acc;
    __syncthreads();
    if (t == 0) {
        float s = red[0] + red[1] + red[2] + red[3];
        if (task < 512)       scores[task] = s + attn_b[task];
        else if (task < 3584) { int j = task - 512; gh[j] = s + b_hh[j]; }
        else                  ce[task - 3584] = s;
    }
}

// D2: softmax(scores) -> attnw (block 0); attn_applied[16 cols per block]
__global__ void k_attn(const float* __restrict__ scores, const float* __restrict__ enc,
                       float* __restrict__ attn_out, float* __restrict__ attn_applied) {
    __shared__ float w[512];
    __shared__ float red[4];
    __shared__ float acc_lds[256];
    __shared__ float sM, sS;
    int t = threadIdx.x, lane = t & 63, wid = t >> 6;
    float s0 = scores[t], s1 = scores[t + 256];
    float m = fmaxf(s0, s1);
    #pragma unroll
    for (int o = 32; o > 0; o >>= 1) m = fmaxf(m, __shfl_xor(m, o, 64));
    if (lane == 0) red[wid] = m;
    __syncthreads();
    if (t == 0) sM = fmaxf(fmaxf(red[0], red[1]), fmaxf(red[2], red[3]));
    __syncthreads();
    float M = sM;
    float e0 = expf(s0 - M), e1 = expf(s1 - M);
    float s = wave_reduce_sum(e0 + e1);
    if (lane == 0) red[wid] = s;
    __syncthreads();
    if (t == 0) sS = red[0] + red[1] + red[2] + red[3];
    __syncthreads();
    float inv = 1.f / sS;
    w[t] = e0 * inv; w[t + 256] = e1 * inv;
    __syncthreads();
    if (blockIdx.x == 0) { attn_out[t] = w[t]; attn_out[t + 256] = w[t + 256]; }
    int col = blockIdx.x * 16 + (t & 15);
    int rc  = t >> 4;
    float acc = 0.f;
    #pragma unroll 8
    for (int l = rc; l < 512; l += 16) acc += w[l] * enc[(size_t)l * H + col];
    acc_lds[t] = acc;
    __syncthreads();
    #pragma unroll
    for (int st = 128; st >= 16; st >>= 1) {
        if (t < st) acc_lds[t] += acc_lds[t + st];
        __syncthreads();
    }
    if (t < 16) attn_applied[blockIdx.x * 16 + t] = acc_lds[t];
}

// D3: x[h] = relu(ce[h] + comb_w[h, H:2H].attn_applied + comb_b[h])  (4KB/row)
__global__ void k_combine2(const float* __restrict__ ce, const float* __restrict__ attn_applied,
                           const float* __restrict__ comb_w, const float* __restrict__ comb_b,
                           float* __restrict__ x) {
    __shared__ float red[4];
    int h = blockIdx.x, t = threadIdx.x, lane = t & 63, wid = t >> 6;
    float acc = dot4(((const float4*)(comb_w + (size_t)h * (2 * H) + H))[t],
                     ((const float4*)attn_applied)[t]);
    acc = wave_reduce_sum(acc);
    if (lane == 0) red[wid] = acc;
    __syncthreads();
    if (t == 0)
        x[h] = fmaxf(ce[h] + red[0] + red[1] + red[2] + red[3] + comb_b[h], 0.f);
}

// D4: gi triple (w_ih only) + GRU gating with precomputed gh -> hnew[h]
__global__ void k_gru2(const float* __restrict__ w_ih, const float* __restrict__ b_ih,
                       const float* __restrict__ gh, const float* __restrict__ x,
                       const float* __restrict__ hidden, float* __restrict__ hnew) {
    __shared__ float red[12];
    int h = blockIdx.x, t = threadIdx.x, lane = t & 63, wid = t >> 6;
    float4 xv = ((const float4*)x)[t];
    float a0 = dot4(((const float4*)(w_ih + (size_t)h * H))[t], xv);
    float a1 = dot4(((const float4*)(w_ih + (size_t)(H + h) * H))[t], xv);
    float a2 = dot4(((const float4*)(w_ih + (size_t)(2 * H + h) * H))[t], xv);
    a0 = wave_reduce_sum(a0);
    a1 = wave_reduce_sum(a1);
    a2 = wave_reduce_sum(a2);
    if (lane == 0) { red[wid * 3] = a0; red[wid * 3 + 1] = a1; red[wid * 3 + 2] = a2; }
    __syncthreads();
    if (t == 0) {
        float g0 = 0.f, g1 = 0.f, g2 = 0.f;
        #pragma unroll
        for (int w2 = 0; w2 < 4; ++w2) {
            g0 += red[w2 * 3]; g1 += red[w2 * 3 + 1]; g2 += red[w2 * 3 + 2];
        }
        float r = 1.f / (1.f + expf(-(g0 + b_ih[h] + gh[h])));
        float z = 1.f / (1.f + expf(-(g1 + b_ih[H + h] + gh[H + h])));
        float n = tanhf(g2 + b_ih[2 * H + h] + r * gh[2 * H + h]);
        hnew[h] = (1.f - z) * n + z * hidden[h];
    }
}

// D5: logits + per-block online (m, sumexp) partials
__global__ void k_logits_lse(const float* __restrict__ out_w, const float* __restrict__ out_b,
                             const float* __restrict__ hvec, float* __restrict__ logits,
                             float* __restrict__ mpart, float* __restrict__ spart) {
    __shared__ float lm[4], ls[4];
    int lane = threadIdx.x & 63, wid = threadIdx.x >> 6;
    int gwave = blockIdx.x * 4 + wid;
    const int nwaves = LOGIT_BLOCKS * 4;
    float4 h4[4];
    #pragma unroll
    for (int j = 0; j < 4; ++j) h4[j] = ((const float4*)hvec)[j * 64 + lane];
    float m = -INFINITY, s = 0.f;
    for (int r = gwave; r < V; r += nwaves) {
        const float4* row = (const float4*)(out_w + (size_t)r * H);
        float acc = 0.f;
        #pragma unroll
        for (int j = 0; j < 4; ++j) acc += dot4(row[j * 64 + lane], h4[j]);
        acc = wave_reduce_sum(acc);
        float logit = acc + out_b[r];
        if (lane == 0) logits[r] = logit;
        if (logit > m) { s = s * expf(m - logit) + 1.f; m = logit; }
        else           { s += expf(logit - m); }
    }
    if (lane == 0) { lm[wid] = m; ls[wid] = s; }
    __syncthreads();
    if (threadIdx.x == 0) {
        float M = fmaxf(fmaxf(lm[0], lm[1]), fmaxf(lm[2], lm[3]));
        float S = 0.f;
        if (M > -INFINITY) {
            #pragma unroll
            for (int i = 0; i < 4; ++i) S += ls[i] * expf(lm[i] - M);
        }
        mpart[blockIdx.x] = M; spart[blockIdx.x] = S;
    }
}

// D6: every block merges the 2048 partials, then subtracts logZ in place
__global__ void k_finalize(const float* __restrict__ mpart, const float* __restrict__ spart,
                           float* __restrict__ out) {
    __shared__ float lm[4], ls[4];
    __shared__ float sLogZ;
    int t = threadIdx.x, lane = t & 63, wid = t >> 6;
    float m = -INFINITY, s = 0.f;
    for (int i = t; i < LOGIT_BLOCKS; i += 256) {
        float m2 = mpart[i], s2 = spart[i];
        float mm = fmaxf(m, m2);
        if (mm > -INFINITY) s = s * expf(m - mm) + s2 * expf(m2 - mm);
        m = mm;
    }
    #pragma unroll
    for (int o = 32; o > 0; o >>= 1) {
        float m2 = __shfl_xor(m, o, 64), s2 = __shfl_xor(s, o, 64);
        float mm = fmaxf(m, m2);
        if (mm > -INFINITY) s = s * expf(m - mm) + s2 * expf(m2 - mm);
        m = mm;
    }
    if (lane == 0) { lm[wid] = m; ls[wid] = s; }
    __syncthreads();
    if (t == 0) {
        float M = fmaxf(fmaxf(lm[0], lm[1]), fmaxf(lm[2], lm[3]));
        float S = 0.f;
        #pragma unroll
        for (int i = 0; i < 4; ++i) S += ls[i] * expf(lm[i] - M);
        sLogZ = M + logf(S);
    }
    __syncthreads();
    int v = blockIdx.x * 256 + t;
    if (v < V) out[v] -= sLogZ;
}

extern "C" void kernel_launch(void* const* d_in, const int* in_sizes, int n_in,
                              void* d_out, int out_size, void* d_ws, size_t ws_size,
                              hipStream_t stream) {
    const int*   input  = (const int*)  d_in[0];
    const float* hidden = (const float*)d_in[1];
    const float* enc    = (const float*)d_in[2];
    const float* emb    = (const float*)d_in[3];
    const float* attn_w = (const float*)d_in[4];
    const float* attn_b = (const float*)d_in[5];
    const float* comb_w = (const float*)d_in[6];
    const float* comb_b = (const float*)d_in[7];
    const float* w_ih   = (const float*)d_in[8];
    const float* w_hh   = (const float*)d_in[9];
    const float* b_ih   = (const float*)d_in[10];
    const float* b_hh   = (const float*)d_in[11];
    const float* out_w  = (const float*)d_in[12];
    const float* out_b  = (const float*)d_in[13];

    float* out   = (float*)d_out;            // [0, V)      log_softmax
    float* hnew  = out + V;                  // [V, V+H)    h_new
    float* attnw = out + V + H;              // [V+H, +L)   attn_weights

    float* ws           = (float*)d_ws;
    float* scores       = ws;                // 512
    float* gh           = ws + 512;          // 3072
    float* ce           = ws + 3584;         // 1024
    float* attn_applied = ws + 4608;         // 1024
    float* xbuf         = ws + 5632;         // 1024
    float* mpart        = ws + 6656;         // 2048
    float* spart        = ws + 8704;         // 2048

    k_pre        <<<4608, 256, 0, stream>>>(emb, input, hidden, attn_w, attn_b,
                                            w_hh, b_hh, comb_w, scores, gh, ce);
    k_attn       <<<64, 256, 0, stream>>>(scores, enc, attnw, attn_applied);
    k_combine2   <<<1024, 256, 0, stream>>>(ce, attn_applied, comb_w, comb_b, xbuf);
    k_gru2       <<<1024, 256, 0, stream>>>(w_ih, b_ih, gh, xbuf, hidden, hnew);
    k_logits_lse <<<LOGIT_BLOCKS, 256, 0, stream>>>(out_w, out_b, hnew, out, mpart, spart);
    k_finalize   <<<(V + 255) / 256, 256, 0, stream>>>(mpart, spart, out);
}